// Round 5
// baseline (145.464 us; speedup 1.0000x reference)
//
#include <hip/hip_runtime.h>
#include <math.h>

#define BLOCK 256
#define UNROLL 12
#define WTILE (64 * UNROLL)          // 768 elements per wave, contiguous 12 KB per array

typedef float vfloat4 __attribute__((ext_vector_type(4)));   // native vec for nontemporal builtin

// theta^2 for rel = qinv(a) * idd.
// rel is (nearly) unit-norm, so atan2(|v|, w) == acos(w / |rel|).
// Hastings acos approx, max abs err ~6.8e-5 rad (tolerance is 2% relative).
__device__ __forceinline__ float theta_sq(vfloat4 qa, vfloat4 qb) {
    float w1 = qa.x, x1 = -qa.y, y1 = -qa.z, z1 = -qa.w;
    float w2 = qb.x, x2 = qb.y,  y2 = qb.z,  z2 = qb.w;
    float w  = w1*w2 - (x1*x2 + y1*y2 + z1*z2);
    float vx = w1*x2 + w2*x1 + (y1*z2 - z1*y2);
    float vy = w1*y2 + w2*y1 + (z1*x2 - x1*z2);
    float vz = w1*z2 + w2*z1 + (x1*y2 - y1*x2);
    float nv2 = vx*vx + vy*vy + vz*vz;
    float nv  = sqrtf(nv2);
    if (nv < 1e-6f) {                    // reference small-angle branch
        float s = 2.0f / w;
        return nv2 * s * s;
    }
    float rn = rsqrtf(w*w + nv2);        // exact normalize (~1.0)
    float c  = w * rn;                   // cos(theta/2) in [-1,1]
    float ac = fabsf(c);
    float p  = ((-0.0187293f*ac + 0.0742610f)*ac - 0.2121144f)*ac + 1.5707288f;
    float r  = sqrtf(fmaxf(1.0f - ac, 0.0f)) * p;            // acos(|c|)
    float acosc = (c >= 0.0f) ? r : (3.14159265358979f - r);
    float theta = 2.0f * acosc;
    return theta * theta;
}

__global__ __launch_bounds__(BLOCK) void geo_loss_kernel(
        const vfloat4* __restrict__ a,
        const vfloat4* __restrict__ idd,
        float* __restrict__ ws, int n) {
    const int tid  = threadIdx.x;
    const int lane = tid & 63;
    const int gw   = (blockIdx.x * BLOCK + tid) >> 6;   // global wave id
    const int wbase = gw * WTILE;
    float acc = 0.0f;

    if (wbase + WTILE <= n) {
        // full wave tile: 12 contiguous 1KB bursts per array, nontemporal
        vfloat4 qa[UNROLL], qb[UNROLL];
        #pragma unroll
        for (int k = 0; k < UNROLL; k++)
            qa[k] = __builtin_nontemporal_load(&a[wbase + k * 64 + lane]);
        #pragma unroll
        for (int k = 0; k < UNROLL; k++)
            qb[k] = __builtin_nontemporal_load(&idd[wbase + k * 64 + lane]);
        #pragma unroll
        for (int k = 0; k < UNROLL; k++)
            acc += theta_sq(qa[k], qb[k]);
    } else if (wbase < n) {
        // tail wave only
        for (int k = 0; k < UNROLL; k++) {
            int idx = wbase + k * 64 + lane;
            if (idx < n) acc += theta_sq(a[idx], idd[idx]);
        }
    }

    // wave-64 reduction
    #pragma unroll
    for (int off = 32; off > 0; off >>= 1)
        acc += __shfl_down(acc, off, 64);
    __shared__ float smem[BLOCK / 64];
    int wid = tid >> 6;
    if (lane == 0) smem[wid] = acc;
    __syncthreads();
    if (tid == 0) {
        float s = smem[0] + smem[1] + smem[2] + smem[3];
        atomicAdd(ws, s);            // device-scope by default on CDNA
    }
}

__global__ void finalize_kernel(const float* __restrict__ ws,
                                float* __restrict__ out) {
    out[0] = sqrtf(ws[0]);
}

extern "C" void kernel_launch(void* const* d_in, const int* in_sizes, int n_in,
                              void* d_out, int out_size, void* d_ws, size_t ws_size,
                              hipStream_t stream) {
    const vfloat4* a   = (const vfloat4*)d_in[0];
    const vfloat4* idd = (const vfloat4*)d_in[1];
    int n = in_sizes[0] / 4;             // 4,000,000 quaternions
    float* ws = (float*)d_ws;

    (void)hipMemsetAsync(ws, 0, sizeof(float), stream);

    int nwaves = (n + WTILE - 1) / WTILE;        // 5209
    int grid   = (nwaves + (BLOCK / 64) - 1) / (BLOCK / 64);   // 1303 blocks
    geo_loss_kernel<<<grid, BLOCK, 0, stream>>>(a, idd, ws, n);
    finalize_kernel<<<1, 1, 0, stream>>>(ws, (float*)d_out);
}

// Round 6
// 144.645 us; speedup vs baseline: 1.0057x; 1.0057x over previous
//
#include <hip/hip_runtime.h>
#include <math.h>

#define BLOCK 256
#define UNROLL 12
#define WTILE (64 * UNROLL)          // 768 elements per wave, contiguous 12 KB per array

// theta^2 for rel = qinv(a) * idd.
// rel is (nearly) unit-norm, so atan2(|v|, w) == acos(w / |rel|).
// Hastings acos approx, max abs err ~6.8e-5 rad (tolerance is 2% relative).
__device__ __forceinline__ float theta_sq(float4 qa, float4 qb) {
    float w1 = qa.x, x1 = -qa.y, y1 = -qa.z, z1 = -qa.w;
    float w2 = qb.x, x2 = qb.y,  y2 = qb.z,  z2 = qb.w;
    float w  = w1*w2 - (x1*x2 + y1*y2 + z1*z2);
    float vx = w1*x2 + w2*x1 + (y1*z2 - z1*y2);
    float vy = w1*y2 + w2*y1 + (z1*x2 - x1*z2);
    float vz = w1*z2 + w2*z1 + (x1*y2 - y1*x2);
    float nv2 = vx*vx + vy*vy + vz*vz;
    float nv  = sqrtf(nv2);
    if (nv < 1e-6f) {                    // reference small-angle branch
        float s = 2.0f / w;
        return nv2 * s * s;
    }
    float rn = rsqrtf(w*w + nv2);        // exact normalize (~1.0)
    float c  = w * rn;                   // cos(theta/2) in [-1,1]
    float ac = fabsf(c);
    float p  = ((-0.0187293f*ac + 0.0742610f)*ac - 0.2121144f)*ac + 1.5707288f;
    float r  = sqrtf(fmaxf(1.0f - ac, 0.0f)) * p;            // acos(|c|)
    float acosc = (c >= 0.0f) ? r : (3.14159265358979f - r);
    float theta = 2.0f * acosc;
    return theta * theta;
}

__global__ __launch_bounds__(BLOCK) void geo_loss_kernel(
        const float4* __restrict__ a,
        const float4* __restrict__ idd,
        float* __restrict__ partials, int n) {
    const int tid  = threadIdx.x;
    const int lane = tid & 63;
    const int gw   = (blockIdx.x * BLOCK + tid) >> 6;   // global wave id
    const int wbase = gw * WTILE;
    float acc = 0.0f;

    if (wbase + WTILE <= n) {
        // full wave tile: 12 contiguous 1KB bursts per array
        float4 qa[UNROLL], qb[UNROLL];
        #pragma unroll
        for (int k = 0; k < UNROLL; k++) qa[k] = a[wbase + k * 64 + lane];
        #pragma unroll
        for (int k = 0; k < UNROLL; k++) qb[k] = idd[wbase + k * 64 + lane];
        #pragma unroll
        for (int k = 0; k < UNROLL; k++) acc += theta_sq(qa[k], qb[k]);
    } else if (wbase < n) {
        // tail wave only
        for (int k = 0; k < UNROLL; k++) {
            int idx = wbase + k * 64 + lane;
            if (idx < n) acc += theta_sq(a[idx], idd[idx]);
        }
    }

    // wave-64 reduction
    #pragma unroll
    for (int off = 32; off > 0; off >>= 1)
        acc += __shfl_down(acc, off, 64);
    __shared__ float smem[BLOCK / 64];
    int wid = tid >> 6;
    if (lane == 0) smem[wid] = acc;
    __syncthreads();
    if (tid == 0)
        partials[blockIdx.x] = smem[0] + smem[1] + smem[2] + smem[3];
}

__global__ __launch_bounds__(BLOCK) void finalize_kernel(
        const float* __restrict__ partials,
        float* __restrict__ out, int nparts) {
    float acc = 0.0f;
    for (int i = threadIdx.x; i < nparts; i += BLOCK)
        acc += partials[i];
    #pragma unroll
    for (int off = 32; off > 0; off >>= 1)
        acc += __shfl_down(acc, off, 64);
    __shared__ float smem[BLOCK / 64];
    int lane = threadIdx.x & 63;
    int wid  = threadIdx.x >> 6;
    if (lane == 0) smem[wid] = acc;
    __syncthreads();
    if (threadIdx.x == 0)
        out[0] = sqrtf(smem[0] + smem[1] + smem[2] + smem[3]);
}

extern "C" void kernel_launch(void* const* d_in, const int* in_sizes, int n_in,
                              void* d_out, int out_size, void* d_ws, size_t ws_size,
                              hipStream_t stream) {
    const float4* a   = (const float4*)d_in[0];
    const float4* idd = (const float4*)d_in[1];
    int n = in_sizes[0] / 4;             // 4,000,000 quaternions
    float* ws = (float*)d_ws;

    int nwaves = (n + WTILE - 1) / WTILE;                      // 5209
    int grid   = (nwaves + (BLOCK / 64) - 1) / (BLOCK / 64);   // 1303 blocks
    geo_loss_kernel<<<grid, BLOCK, 0, stream>>>(a, idd, ws, n);
    finalize_kernel<<<1, BLOCK, 0, stream>>>(ws, (float*)d_out, grid);
}

// Round 7
// 143.301 us; speedup vs baseline: 1.0151x; 1.0094x over previous
//
#include <hip/hip_runtime.h>
#include <math.h>

#define BLOCK 256                 // 4 waves/block
#define GRID  1024                // 4096 waves, 4 blocks/CU (LDS-bound: 32 KB/block)
#define NW    (GRID * (BLOCK/64)) // total waves = 4096
#define SELEM 256                 // elements per wave-stage (4 KB per array)

// theta^2 for rel = qinv(a) * idd.  Hastings acos approx, err ~6.8e-5 rad.
__device__ __forceinline__ float theta_sq(float4 qa, float4 qb) {
    float w1 = qa.x, x1 = -qa.y, y1 = -qa.z, z1 = -qa.w;
    float w2 = qb.x, x2 = qb.y,  y2 = qb.z,  z2 = qb.w;
    float w  = w1*w2 - (x1*x2 + y1*y2 + z1*z2);
    float vx = w1*x2 + w2*x1 + (y1*z2 - z1*y2);
    float vy = w1*y2 + w2*y1 + (z1*x2 - x1*z2);
    float vz = w1*z2 + w2*z1 + (x1*y2 - y1*x2);
    float nv2 = vx*vx + vy*vy + vz*vz;
    float nv  = sqrtf(nv2);
    if (nv < 1e-6f) {                    // reference small-angle branch
        float s = 2.0f / w;
        return nv2 * s * s;
    }
    float rn = rsqrtf(w*w + nv2);
    float c  = w * rn;                   // cos(theta/2) in [-1,1]
    float ac = fabsf(c);
    float p  = ((-0.0187293f*ac + 0.0742610f)*ac - 0.2121144f)*ac + 1.5707288f;
    float r  = sqrtf(fmaxf(1.0f - ac, 0.0f)) * p;
    float acosc = (c >= 0.0f) ? r : (3.14159265358979f - r);
    float theta = 2.0f * acosc;
    return theta * theta;
}

__global__ __launch_bounds__(BLOCK) void geo_loss_kernel(
        const float4* __restrict__ a,
        const float4* __restrict__ idd,
        float* __restrict__ partials, int n) {
    __shared__ float4 sA[4][SELEM];      // 16 KB
    __shared__ float4 sB[4][SELEM];      // 16 KB
    const int tid  = threadIdx.x;
    const int lane = tid & 63;
    const int wid  = tid >> 6;
    const int gwave = blockIdx.x * (BLOCK / 64) + wid;
    const int nstages = n / SELEM;       // 15625 for N=4M
    float acc = 0.0f;

    for (int s = gwave; s < nstages; s += NW) {
        const int ebase = s * SELEM;
        // stage 4 KB of each array into this wave's LDS slot via LDS-DMA.
        // HW semantics: lane i's 16 B land at (wave-uniform lds base) + i*16.
        #pragma unroll
        for (int k = 0; k < 4; k++) {
            __builtin_amdgcn_global_load_lds(
                (const __attribute__((address_space(1))) void*)(a + ebase + k * 64 + lane),
                (__attribute__((address_space(3))) void*)(&sA[wid][k * 64]),
                16, 0, 0);
        }
        #pragma unroll
        for (int k = 0; k < 4; k++) {
            __builtin_amdgcn_global_load_lds(
                (const __attribute__((address_space(1))) void*)(idd + ebase + k * 64 + lane),
                (__attribute__((address_space(3))) void*)(&sB[wid][k * 64]),
                16, 0, 0);
        }
        __builtin_amdgcn_s_waitcnt(0x0F70);   // vmcnt(0) only (exp=7, lgkm=15)
        #pragma unroll
        for (int j = 0; j < 4; j++)
            acc += theta_sq(sA[wid][j * 64 + lane], sB[wid][j * 64 + lane]);
    }

    // generic tail (empty for N=4M since 4e6 % 256 == 0)
    for (int idx = nstages * SELEM + blockIdx.x * BLOCK + tid; idx < n;
         idx += GRID * BLOCK)
        acc += theta_sq(a[idx], idd[idx]);

    // wave-64 reduction
    #pragma unroll
    for (int off = 32; off > 0; off >>= 1)
        acc += __shfl_down(acc, off, 64);
    __shared__ float smem[BLOCK / 64];
    if (lane == 0) smem[wid] = acc;
    __syncthreads();
    if (tid == 0)
        partials[blockIdx.x] = smem[0] + smem[1] + smem[2] + smem[3];
}

__global__ __launch_bounds__(BLOCK) void finalize_kernel(
        const float* __restrict__ partials,
        float* __restrict__ out, int nparts) {
    float acc = 0.0f;
    for (int i = threadIdx.x; i < nparts; i += BLOCK)
        acc += partials[i];
    #pragma unroll
    for (int off = 32; off > 0; off >>= 1)
        acc += __shfl_down(acc, off, 64);
    __shared__ float smem[BLOCK / 64];
    int lane = threadIdx.x & 63;
    int wid  = threadIdx.x >> 6;
    if (lane == 0) smem[wid] = acc;
    __syncthreads();
    if (threadIdx.x == 0)
        out[0] = sqrtf(smem[0] + smem[1] + smem[2] + smem[3]);
}

extern "C" void kernel_launch(void* const* d_in, const int* in_sizes, int n_in,
                              void* d_out, int out_size, void* d_ws, size_t ws_size,
                              hipStream_t stream) {
    const float4* a   = (const float4*)d_in[0];
    const float4* idd = (const float4*)d_in[1];
    int n = in_sizes[0] / 4;             // 4,000,000 quaternions
    float* ws = (float*)d_ws;

    geo_loss_kernel<<<GRID, BLOCK, 0, stream>>>(a, idd, ws, n);
    finalize_kernel<<<1, BLOCK, 0, stream>>>(ws, (float*)d_out, GRID);
}

// Round 8
// 141.736 us; speedup vs baseline: 1.0263x; 1.0110x over previous
//
#include <hip/hip_runtime.h>
#include <math.h>

#define BLOCK 512
#define UNROLL 4
#define TILE (BLOCK * UNROLL)     // 2048 elements per block, contiguous

// theta^2 for rel = qinv(a) * idd.
// rel is (nearly) unit-norm, so atan2(|v|, w) == acos(w / |rel|).
// Hastings acos approx, max abs err ~6.8e-5 rad (tolerance is 2% relative).
__device__ __forceinline__ float theta_sq(float4 qa, float4 qb) {
    float w1 = qa.x, x1 = -qa.y, y1 = -qa.z, z1 = -qa.w;
    float w2 = qb.x, x2 = qb.y,  y2 = qb.z,  z2 = qb.w;
    float w  = w1*w2 - (x1*x2 + y1*y2 + z1*z2);
    float vx = w1*x2 + w2*x1 + (y1*z2 - z1*y2);
    float vy = w1*y2 + w2*y1 + (z1*x2 - x1*z2);
    float vz = w1*z2 + w2*z1 + (x1*y2 - y1*x2);
    float nv2 = vx*vx + vy*vy + vz*vz;
    float nv  = sqrtf(nv2);
    if (nv < 1e-6f) {                    // reference small-angle branch
        float s = 2.0f / w;
        return nv2 * s * s;
    }
    float rn = rsqrtf(w*w + nv2);        // exact normalize (~1.0)
    float c  = w * rn;                   // cos(theta/2) in [-1,1]
    float ac = fabsf(c);
    float p  = ((-0.0187293f*ac + 0.0742610f)*ac - 0.2121144f)*ac + 1.5707288f;
    float r  = sqrtf(fmaxf(1.0f - ac, 0.0f)) * p;            // acos(|c|)
    float acosc = (c >= 0.0f) ? r : (3.14159265358979f - r);
    float theta = 2.0f * acosc;
    return theta * theta;
}

// 100%-occupancy probe: VGPR<=64 via launch_bounds, 8 loads in flight/thread.
__global__ __launch_bounds__(BLOCK, 8) void geo_loss_kernel(
        const float4* __restrict__ a,
        const float4* __restrict__ idd,
        float* __restrict__ partials, int n) {
    const int tid  = threadIdx.x;
    const int base = blockIdx.x * TILE + tid;
    float acc = 0.0f;

    if (base + (UNROLL - 1) * BLOCK < n) {
        // full tile — block-uniform branch, one clause of 8 dwordx4
        float4 qa[UNROLL], qb[UNROLL];
        #pragma unroll
        for (int k = 0; k < UNROLL; k++) qa[k] = a[base + k * BLOCK];
        #pragma unroll
        for (int k = 0; k < UNROLL; k++) qb[k] = idd[base + k * BLOCK];
        #pragma unroll
        for (int k = 0; k < UNROLL; k++) acc += theta_sq(qa[k], qb[k]);
    } else {
        for (int k = 0; k < UNROLL; k++) {
            int idx = base + k * BLOCK;
            if (idx < n) acc += theta_sq(a[idx], idd[idx]);
        }
    }

    // wave-64 reduction
    #pragma unroll
    for (int off = 32; off > 0; off >>= 1)
        acc += __shfl_down(acc, off, 64);
    __shared__ float smem[BLOCK / 64];
    int lane = tid & 63;
    int wid  = tid >> 6;
    if (lane == 0) smem[wid] = acc;
    __syncthreads();
    if (tid == 0) {
        float s = 0.0f;
        #pragma unroll
        for (int i = 0; i < BLOCK / 64; i++) s += smem[i];
        partials[blockIdx.x] = s;
    }
}

__global__ __launch_bounds__(256) void finalize_kernel(
        const float* __restrict__ partials,
        float* __restrict__ out, int nparts) {
    float acc = 0.0f;
    for (int i = threadIdx.x; i < nparts; i += 256)
        acc += partials[i];
    #pragma unroll
    for (int off = 32; off > 0; off >>= 1)
        acc += __shfl_down(acc, off, 64);
    __shared__ float smem[4];
    int lane = threadIdx.x & 63;
    int wid  = threadIdx.x >> 6;
    if (lane == 0) smem[wid] = acc;
    __syncthreads();
    if (threadIdx.x == 0)
        out[0] = sqrtf(smem[0] + smem[1] + smem[2] + smem[3]);
}

extern "C" void kernel_launch(void* const* d_in, const int* in_sizes, int n_in,
                              void* d_out, int out_size, void* d_ws, size_t ws_size,
                              hipStream_t stream) {
    const float4* a   = (const float4*)d_in[0];
    const float4* idd = (const float4*)d_in[1];
    int n = in_sizes[0] / 4;             // 4,000,000 quaternions
    float* ws = (float*)d_ws;

    int grid = (n + TILE - 1) / TILE;    // 1954 blocks
    geo_loss_kernel<<<grid, BLOCK, 0, stream>>>(a, idd, ws, n);
    finalize_kernel<<<1, 256, 0, stream>>>(ws, (float*)d_out, grid);
}